// Round 4
// baseline (1181.820 us; speedup 1.0000x reference)
//
#include <hip/hip_runtime.h>

#define NN 50000
#define NE 800000
#define NT 850000   // NE + NN self loops
#define NG 512

// ==================== reduction / math helpers ====================

template <int CTRL>
__device__ __forceinline__ float dpp_add(float x) {
  int y = __builtin_amdgcn_update_dpp(0, __float_as_int(x), CTRL, 0xF, 0xF, true);
  return x + __int_as_float(y);
}

// full 64-lane sum, broadcast to all lanes
__device__ __forceinline__ float wave_sum(float x) {
  x = dpp_add<0xB1>(x);    // quad_perm [1,0,3,2]  (xor1)
  x = dpp_add<0x4E>(x);    // quad_perm [2,3,0,1]  (xor2)
  x = dpp_add<0x124>(x);   // row_ror:4
  x = dpp_add<0x128>(x);   // row_ror:8
  x = x + __int_as_float(__builtin_amdgcn_ds_swizzle(__float_as_int(x), 0x401F)); // xor16
  auto p = __builtin_amdgcn_permlane32_swap(__float_as_uint(x), __float_as_uint(x), false, false);
  return __uint_as_float(p[0]) + __uint_as_float(p[1]);   // + xor32
}

__device__ __forceinline__ float exp2_fast(float x) {
#if __has_builtin(__builtin_amdgcn_exp2f)
  return __builtin_amdgcn_exp2f(x);
#else
  return exp2f(x);
#endif
}

__device__ __forceinline__ float lrelu(float t) { return fmaxf(t, 0.2f * t); }

// packed f32 FMA: d += a.{lo or hi broadcast} * b (per-component)
__device__ __forceinline__ void pk_l(float2& d, float2 a, float2 b) {
  asm("v_pk_fma_f32 %0, %1, %2, %0 op_sel_hi:[0,1,1]" : "+v"(d) : "v"(a), "v"(b));
}
__device__ __forceinline__ void pk_h(float2& d, float2 a, float2 b) {
  asm("v_pk_fma_f32 %0, %1, %2, %0 op_sel:[1,0,0]" : "+v"(d) : "v"(a), "v"(b));
}

// ==================== edge bucket sort (by dst) ====================

__global__ void k_hist(const int* __restrict__ dst, int* __restrict__ cnt) {
  int i = blockIdx.x * blockDim.x + threadIdx.x;
  if (i < NT) {
    int d = (i < NE) ? dst[i] : (i - NE);
    atomicAdd(&cnt[d], 1);
  }
}

__global__ __launch_bounds__(1024)
void k_scan(const int* __restrict__ cnt, int* __restrict__ offs) {
  __shared__ int sh[1024];
  int tid = threadIdx.x;
  const int CH = (NN + 1023) / 1024;
  int base = tid * CH;
  int s = 0;
  for (int i = 0; i < CH; ++i) {
    int idx = base + i;
    if (idx < NN) s += cnt[idx];
  }
  sh[tid] = s;
  __syncthreads();
  for (int off = 1; off < 1024; off <<= 1) {
    int t = (tid >= off) ? sh[tid - off] : 0;
    __syncthreads();
    sh[tid] += t;
    __syncthreads();
  }
  int prefix = (tid > 0) ? sh[tid - 1] : 0;
  for (int i = 0; i < CH; ++i) {
    int idx = base + i;
    if (idx < NN) {
      offs[idx] = prefix;
      prefix += cnt[idx];
    }
  }
  if (tid == 1023) offs[NN] = sh[1023];
}

__global__ void k_scatter(const int* __restrict__ src, const int* __restrict__ dst,
                          const int* __restrict__ offs, int* __restrict__ cur,
                          int* __restrict__ srt) {
  int i = blockIdx.x * blockDim.x + threadIdx.x;
  if (i < NT) {
    int s, d;
    if (i < NE) { s = src[i]; d = dst[i]; }
    else        { s = d = i - NE; }
    int pos = offs[d] + atomicAdd(&cur[d], 1);
    srt[pos] = s;
  }
}

// ==================== dual GEMM, single-barrier double-buffered LDS ====================
// C1 = A@W1^T + b1, C2 = A@W2^T + b2.  A:[M,K] W:[FO,K] row-major.
// 256 threads. CT col-threads (4 cols each), 256/CT row-threads (8 rows each).
// CT=16: 128x64 tile.  CT=8: 256x32 tile (skinny FO).  K-tile = 16.

template <int CT>
__global__ __launch_bounds__(256, 4)
void k_gemm_dual(const float* __restrict__ A, int M, int K, int FO,
                 const float* __restrict__ W1, const float* __restrict__ bias1,
                 const float* __restrict__ W2, const float* __restrict__ bias2,
                 float* __restrict__ C1, float* __restrict__ C2) {
  constexpr int BN = CT * 4;            // cols per tile
  constexpr int BR = (256 / CT) * 8;    // rows per tile
  constexpr int APAD = BR + 4;
  constexpr int BPAD = BN + 4;
  constexpr int AF4 = BR * 16 / 4 / 256;   // A float4 per thread (2 or 4)
  __shared__ float As[2][16][APAD];
  __shared__ float Bs[2][2][16][BPAD];

  int tid = threadIdx.x;
  int tx = tid % CT, ty = tid / CT;
  int mb = blockIdx.x * BR, nb = blockIdx.y * BN;
  int nkt = (K + 15) >> 4;
  bool kvec = ((K & 3) == 0);

  float4 sa[AF4], sb1, sb2;

  auto ldrow = [&](const float* P, int row, int lim, int k0, int kq) -> float4 {
    float4 v = make_float4(0.f, 0.f, 0.f, 0.f);
    if (row < lim) {
      if (kvec && k0 + kq + 3 < K) {
        v = *(const float4*)&P[(size_t)row * K + k0 + kq];
      } else {
        float t[4];
#pragma unroll
        for (int i = 0; i < 4; ++i)
          t[i] = (k0 + kq + i < K) ? P[(size_t)row * K + k0 + kq + i] : 0.f;
        v = make_float4(t[0], t[1], t[2], t[3]);
      }
    }
    return v;
  };

  auto loadg = [&](int kt) {
    int k0 = kt * 16;
#pragma unroll
    for (int q = 0; q < AF4; ++q) {
      int f4 = q * 256 + tid;
      sa[q] = ldrow(A, mb + (f4 >> 2), M, k0, (f4 & 3) * 4);
    }
    if constexpr (CT == 16) {
      int row = tid >> 2, kq = (tid & 3) * 4;
      sb1 = ldrow(W1, nb + row, FO, k0, kq);
      sb2 = ldrow(W2, nb + row, FO, k0, kq);
    } else {
      const float* W = (tid < 128) ? W1 : W2;
      int t = tid & 127;
      sb1 = ldrow(W, nb + (t >> 2), FO, k0, (t & 3) * 4);
    }
  };

  auto stlds = [&](int c) {
#pragma unroll
    for (int q = 0; q < AF4; ++q) {
      int f4 = q * 256 + tid;
      int row = f4 >> 2, kq = (f4 & 3) * 4;
      As[c][kq + 0][row] = sa[q].x; As[c][kq + 1][row] = sa[q].y;
      As[c][kq + 2][row] = sa[q].z; As[c][kq + 3][row] = sa[q].w;
    }
    if constexpr (CT == 16) {
      int row = tid >> 2, kq = (tid & 3) * 4;
      Bs[c][0][kq + 0][row] = sb1.x; Bs[c][0][kq + 1][row] = sb1.y;
      Bs[c][0][kq + 2][row] = sb1.z; Bs[c][0][kq + 3][row] = sb1.w;
      Bs[c][1][kq + 0][row] = sb2.x; Bs[c][1][kq + 1][row] = sb2.y;
      Bs[c][1][kq + 2][row] = sb2.z; Bs[c][1][kq + 3][row] = sb2.w;
    } else {
      int mat = (tid < 128) ? 0 : 1;
      int t = tid & 127;
      int row = t >> 2, kq = (t & 3) * 4;
      Bs[c][mat][kq + 0][row] = sb1.x; Bs[c][mat][kq + 1][row] = sb1.y;
      Bs[c][mat][kq + 2][row] = sb1.z; Bs[c][mat][kq + 3][row] = sb1.w;
    }
  };

  float2 c1[8][2], c2[8][2];
#pragma unroll
  for (int r = 0; r < 8; ++r)
#pragma unroll
    for (int j = 0; j < 2; ++j) {
      c1[r][j] = make_float2(0.f, 0.f);
      c2[r][j] = make_float2(0.f, 0.f);
    }

  loadg(0);
  stlds(0);
  __syncthreads();

  for (int t = 0; t < nkt; ++t) {
    int c = t & 1;
    bool more = (t + 1 < nkt);
    if (more) loadg(t + 1);
#pragma unroll
    for (int k = 0; k < 16; ++k) {
      float4 av0 = *(const float4*)&As[c][k][ty * 8 + 0];
      float4 av1 = *(const float4*)&As[c][k][ty * 8 + 4];
      float4 bv1 = *(const float4*)&Bs[c][0][k][tx * 4];
      float4 bv2 = *(const float4*)&Bs[c][1][k][tx * 4];
      float2 f1a = make_float2(bv1.x, bv1.y), f1b = make_float2(bv1.z, bv1.w);
      float2 f2a = make_float2(bv2.x, bv2.y), f2b = make_float2(bv2.z, bv2.w);
      float2 a01 = make_float2(av0.x, av0.y), a23 = make_float2(av0.z, av0.w);
      float2 a45 = make_float2(av1.x, av1.y), a67 = make_float2(av1.z, av1.w);
#define PKROW(rp, a)                                                       \
      pk_l(c1[2 * rp + 0][0], a, f1a); pk_l(c1[2 * rp + 0][1], a, f1b);    \
      pk_h(c1[2 * rp + 1][0], a, f1a); pk_h(c1[2 * rp + 1][1], a, f1b);    \
      pk_l(c2[2 * rp + 0][0], a, f2a); pk_l(c2[2 * rp + 0][1], a, f2b);    \
      pk_h(c2[2 * rp + 1][0], a, f2a); pk_h(c2[2 * rp + 1][1], a, f2b);
      PKROW(0, a01) PKROW(1, a23) PKROW(2, a45) PKROW(3, a67)
#undef PKROW
    }
    if (more) stlds(c ^ 1);
    __syncthreads();
  }

  int col = nb + tx * 4;
  if (col + 3 < FO + 1 && col < FO) {  // FO multiple of 4 in all layers
    float4 bb1 = *(const float4*)&bias1[col];
    float4 bb2 = *(const float4*)&bias2[col];
#pragma unroll
    for (int r = 0; r < 8; ++r) {
      int m = mb + ty * 8 + r;
      if (m >= M) continue;
      float4 o1 = make_float4(c1[r][0].x + bb1.x, c1[r][0].y + bb1.y,
                              c1[r][1].x + bb1.z, c1[r][1].y + bb1.w);
      float4 o2 = make_float4(c2[r][0].x + bb2.x, c2[r][0].y + bb2.y,
                              c2[r][1].x + bb2.z, c2[r][1].y + bb2.w);
      *(float4*)&C1[(size_t)m * FO + col] = o1;
      *(float4*)&C2[(size_t)m * FO + col] = o2;
    }
  }
}

// ==================== GAT edge phase, H=3 C=64: one node per 64-thread block ====================

#define LDX(s, X0, X1, X2) { int off_ = (s) * 192 + lane; \
  X0 = xl[off_]; X1 = xl[off_ + 64]; X2 = xl[off_ + 128]; }

__global__ __launch_bounds__(64)
void k_gat3(const float* __restrict__ xl, const float* __restrict__ xr,
            const float* __restrict__ att, const float* __restrict__ bias,
            const int* __restrict__ offs, const int* __restrict__ srt,
            float* __restrict__ out, int relu) {
  const float L2E = 1.4426950408889634f;
  int lane = threadIdx.x;
  int n = blockIdx.x;
  float xr0 = xr[n * 192 + lane], xr1 = xr[n * 192 + 64 + lane], xr2 = xr[n * 192 + 128 + lane];
  float at0 = att[lane] * L2E, at1 = att[64 + lane] * L2E, at2 = att[128 + lane] * L2E;
  float m0 = -1e30f, m1 = -1e30f, m2 = -1e30f;
  float d0 = 0.f, d1 = 0.f, d2 = 0.f;
  float a0 = 0.f, a1 = 0.f, a2 = 0.f;
  int e0 = offs[n], e1 = offs[n + 1];

  bool vA1 = (e0 + 1 < e1);
  int sA0 = srt[e0];
  int sA1 = vA1 ? srt[e0 + 1] : sA0;
  float XA0, XA1, XA2, XB0, XB1, XB2;
  LDX(sA0, XA0, XA1, XA2);
  LDX(sA1, XB0, XB1, XB2);

  for (int j = e0; j < e1; j += 2) {
    bool hn = (j + 2) < e1;
    bool vC1 = false;
    float YA0 = 0.f, YA1 = 0.f, YA2 = 0.f, YB0 = 0.f, YB1 = 0.f, YB2 = 0.f;
    if (hn) {
      int sC0 = srt[j + 2];
      vC1 = (j + 3 < e1);
      int sC1 = vC1 ? srt[j + 3] : sC0;
      LDX(sC0, YA0, YA1, YA2);
      LDX(sC1, YB0, YB1, YB2);
    }
    float r0 = lrelu(XA0 + xr0) * at0;
    float r1 = lrelu(XA1 + xr1) * at1;
    float r2 = lrelu(XA2 + xr2) * at2;
    float r3 = lrelu(XB0 + xr0) * at0;
    float r4 = lrelu(XB1 + xr1) * at1;
    float r5 = lrelu(XB2 + xr2) * at2;
    r0 = wave_sum(r0); r1 = wave_sum(r1); r2 = wave_sum(r2);
    r3 = wave_sum(r3); r4 = wave_sum(r4); r5 = wave_sum(r5);

    float eb0 = vA1 ? r3 : -1e30f;
    float eb1 = vA1 ? r4 : -1e30f;
    float eb2 = vA1 ? r5 : -1e30f;
    float pm0 = fmaxf(r0, eb0), pm1 = fmaxf(r1, eb1), pm2 = fmaxf(r2, eb2);
    float g = fmaxf(fmaxf(pm0 - m0, pm1 - m1), pm2 - m2);
    if (g > 11.0f) {   // rare rescale (defer-max); log2 domain
      float nm0 = fmaxf(m0, pm0), nm1 = fmaxf(m1, pm1), nm2 = fmaxf(m2, pm2);
      float s0 = exp2_fast(m0 - nm0), s1 = exp2_fast(m1 - nm1), s2 = exp2_fast(m2 - nm2);
      d0 *= s0; a0 *= s0; m0 = nm0;
      d1 *= s1; a1 *= s1; m1 = nm1;
      d2 *= s2; a2 *= s2; m2 = nm2;
    }
    float p00 = exp2_fast(r0 - m0), p10 = exp2_fast(eb0 - m0);
    float p01 = exp2_fast(r1 - m1), p11 = exp2_fast(eb1 - m1);
    float p02 = exp2_fast(r2 - m2), p12 = exp2_fast(eb2 - m2);
    d0 += p00 + p10;
    d1 += p01 + p11;
    d2 += p02 + p12;
    a0 = fmaf(p00, XA0, fmaf(p10, XB0, a0));
    a1 = fmaf(p01, XA1, fmaf(p11, XB1, a1));
    a2 = fmaf(p02, XA2, fmaf(p12, XB2, a2));
    if (hn) {
      XA0 = YA0; XA1 = YA1; XA2 = YA2;
      XB0 = YB0; XB1 = YB1; XB2 = YB2;
      vA1 = vC1;
    }
  }
  float v0 = a0 / d0 + bias[lane];
  float v1 = a1 / d1 + bias[64 + lane];
  float v2 = a2 / d2 + bias[128 + lane];
  if (relu) { v0 = fmaxf(v0, 0.f); v1 = fmaxf(v1, 0.f); v2 = fmaxf(v2, 0.f); }
  out[n * 192 + lane] = v0;
  out[n * 192 + 64 + lane] = v1;
  out[n * 192 + 128 + lane] = v2;
}

// ==================== GAT layer 3 (H=1, C=20) fused with global_add_pool ====================

__global__ __launch_bounds__(64)
void k_gat1(const float* __restrict__ xl, const float* __restrict__ xr,
            const float* __restrict__ att, const float* __restrict__ bias,
            const int* __restrict__ offs, const int* __restrict__ srt,
            const int* __restrict__ batch, float* __restrict__ gout) {
  const float L2E = 1.4426950408889634f;
  int lane = threadIdx.x;
  int n = blockIdx.x;
  int ll = (lane < 20) ? lane : 0;
  float xrv = xr[n * 20 + ll];
  float ats = (lane < 20) ? att[lane] * L2E : 0.f;
  float m = -1e30f, d = 0.f, acc = 0.f;
  int e0 = offs[n], e1 = offs[n + 1];

  bool vA1 = (e0 + 1 < e1);
  int sA0 = srt[e0];
  int sA1 = vA1 ? srt[e0 + 1] : sA0;
  float XA = xl[sA0 * 20 + ll];
  float XB = xl[sA1 * 20 + ll];

  for (int j = e0; j < e1; j += 2) {
    bool hn = (j + 2) < e1;
    bool vC1 = false;
    float YA = 0.f, YB = 0.f;
    if (hn) {
      int sC0 = srt[j + 2];
      vC1 = (j + 3 < e1);
      int sC1 = vC1 ? srt[j + 3] : sC0;
      YA = xl[sC0 * 20 + ll];
      YB = xl[sC1 * 20 + ll];
    }
    float r0 = lrelu(XA + xrv) * ats;
    float r1 = lrelu(XB + xrv) * ats;
    r0 = wave_sum(r0);
    r1 = wave_sum(r1);
    float eb = vA1 ? r1 : -1e30f;
    float pm = fmaxf(r0, eb);
    if (pm - m > 11.0f) {
      float nm = fmaxf(m, pm);
      float s = exp2_fast(m - nm);
      d *= s; acc *= s; m = nm;
    }
    float p0 = exp2_fast(r0 - m), p1 = exp2_fast(eb - m);
    d += p0 + p1;
    acc = fmaf(p0, XA, fmaf(p1, XB, acc));
    if (hn) { XA = YA; XB = YB; vA1 = vC1; }
  }
  if (lane < 20) {
    float v = acc / d + bias[lane];
    atomicAdd(&gout[batch[n] * 20 + lane], v);
  }
}

// ==================== launch ====================

extern "C" void kernel_launch(void* const* d_in, const int* in_sizes, int n_in,
                              void* d_out, int out_size, void* d_ws, size_t ws_size,
                              hipStream_t stream) {
  const float* x = (const float*)d_in[0];
  const int* src = (const int*)d_in[1];
  const int* dst = src + NE;
  const int* batch = (const int*)d_in[2];
  const float *Wl[4], *bl[4], *Wr[4], *br[4], *att[4], *bb[4];
  for (int li = 0; li < 4; ++li) {
    Wl[li]  = (const float*)d_in[3 + li * 6 + 0];
    bl[li]  = (const float*)d_in[3 + li * 6 + 1];
    Wr[li]  = (const float*)d_in[3 + li * 6 + 2];
    br[li]  = (const float*)d_in[3 + li * 6 + 3];
    att[li] = (const float*)d_in[3 + li * 6 + 4];
    bb[li]  = (const float*)d_in[3 + li * 6 + 5];
  }

  char* p = (char*)d_ws;
  auto alloc = [&](size_t bytes) {
    char* r = p;
    p += (bytes + 255) & ~(size_t)255;
    return r;
  };
  float* xl  = (float*)alloc((size_t)NN * 192 * 4);
  float* xr  = (float*)alloc((size_t)NN * 192 * 4);
  float* hb  = (float*)alloc((size_t)NN * 192 * 4);
  int* srt   = (int*)alloc((size_t)NT * 4);
  int* offs  = (int*)alloc((size_t)(NN + 1) * 4);
  int* cnt   = (int*)alloc((size_t)NN * 4);
  int* cur   = (int*)alloc((size_t)NN * 4);

  hipMemsetAsync(cnt, 0, (size_t)NN * 4, stream);
  hipMemsetAsync(cur, 0, (size_t)NN * 4, stream);
  hipMemsetAsync(d_out, 0, (size_t)NG * 20 * 4, stream);

  k_hist<<<(NT + 255) / 256, 256, 0, stream>>>(dst, cnt);
  k_scan<<<1, 1024, 0, stream>>>(cnt, offs);
  k_scatter<<<(NT + 255) / 256, 256, 0, stream>>>(src, dst, offs, cur, srt);

  // layer 0: FI=11, FO=192
  {
    dim3 g((NN + 127) / 128, 3);
    k_gemm_dual<16><<<g, 256, 0, stream>>>(x, NN, 11, 192, Wl[0], bl[0], Wr[0], br[0], xl, xr);
    k_gat3<<<NN, 64, 0, stream>>>(xl, xr, att[0], bb[0], offs, srt, hb, 1);
  }
  // layers 1,2: FI=192, FO=192
  for (int li = 1; li <= 2; ++li) {
    dim3 g((NN + 127) / 128, 3);
    k_gemm_dual<16><<<g, 256, 0, stream>>>(hb, NN, 192, 192, Wl[li], bl[li], Wr[li], br[li], xl, xr);
    k_gat3<<<NN, 64, 0, stream>>>(xl, xr, att[li], bb[li], offs, srt, hb, 1);
  }
  // layer 3: FI=192, FO=20, skinny tile (256x32), fused pool
  {
    dim3 g((NN + 255) / 256, 1);
    k_gemm_dual<8><<<g, 256, 0, stream>>>(hb, NN, 192, 20, Wl[3], bl[3], Wr[3], br[3], xl, xr);
    k_gat1<<<NN, 64, 0, stream>>>(xl, xr, att[3], bb[3], offs, srt, batch, (float*)d_out);
  }
}

// Round 5
// 826.987 us; speedup vs baseline: 1.4291x; 1.4291x over previous
//
#include <hip/hip_runtime.h>

#define NN 50000
#define NE 800000
#define NT 850000   // NE + NN self loops
#define NG 512

// ==================== reduction / math helpers ====================

template <int CTRL>
__device__ __forceinline__ float dpp_add(float x) {
  int y = __builtin_amdgcn_update_dpp(0, __float_as_int(x), CTRL, 0xF, 0xF, true);
  return x + __int_as_float(y);
}

// full 64-lane sum, broadcast to all lanes
__device__ __forceinline__ float wave_sum(float x) {
  x = dpp_add<0xB1>(x);    // quad_perm [1,0,3,2]  (xor1)
  x = dpp_add<0x4E>(x);    // quad_perm [2,3,0,1]  (xor2)
  x = dpp_add<0x124>(x);   // row_ror:4
  x = dpp_add<0x128>(x);   // row_ror:8
  x = x + __int_as_float(__builtin_amdgcn_ds_swizzle(__float_as_int(x), 0x401F)); // xor16
  auto p = __builtin_amdgcn_permlane32_swap(__float_as_uint(x), __float_as_uint(x), false, false);
  return __uint_as_float(p[0]) + __uint_as_float(p[1]);   // + xor32
}

__device__ __forceinline__ float exp2_fast(float x) {
#if __has_builtin(__builtin_amdgcn_exp2f)
  return __builtin_amdgcn_exp2f(x);
#else
  return exp2f(x);
#endif
}

__device__ __forceinline__ float lrelu(float t) { return fmaxf(t, 0.2f * t); }

// packed f32 FMA: d += a.{lo or hi broadcast} * b (per-component)
__device__ __forceinline__ void pk_l(float2& d, float2 a, float2 b) {
  asm("v_pk_fma_f32 %0, %1, %2, %0 op_sel_hi:[0,1,1]" : "+v"(d) : "v"(a), "v"(b));
}
__device__ __forceinline__ void pk_h(float2& d, float2 a, float2 b) {
  asm("v_pk_fma_f32 %0, %1, %2, %0 op_sel:[1,0,0]" : "+v"(d) : "v"(a), "v"(b));
}

// ==================== edge bucket sort (by dst) ====================

__global__ void k_hist(const int* __restrict__ dst, int* __restrict__ cnt) {
  int i = blockIdx.x * blockDim.x + threadIdx.x;
  if (i < NT) {
    int d = (i < NE) ? dst[i] : (i - NE);
    atomicAdd(&cnt[d], 1);
  }
}

__global__ __launch_bounds__(1024)
void k_scan(const int* __restrict__ cnt, int* __restrict__ offs) {
  __shared__ int sh[1024];
  int tid = threadIdx.x;
  const int CH = (NN + 1023) / 1024;
  int base = tid * CH;
  int s = 0;
  for (int i = 0; i < CH; ++i) {
    int idx = base + i;
    if (idx < NN) s += cnt[idx];
  }
  sh[tid] = s;
  __syncthreads();
  for (int off = 1; off < 1024; off <<= 1) {
    int t = (tid >= off) ? sh[tid - off] : 0;
    __syncthreads();
    sh[tid] += t;
    __syncthreads();
  }
  int prefix = (tid > 0) ? sh[tid - 1] : 0;
  for (int i = 0; i < CH; ++i) {
    int idx = base + i;
    if (idx < NN) {
      offs[idx] = prefix;
      prefix += cnt[idx];
    }
  }
  if (tid == 1023) offs[NN] = sh[1023];
}

__global__ void k_scatter(const int* __restrict__ src, const int* __restrict__ dst,
                          const int* __restrict__ offs, int* __restrict__ cur,
                          int* __restrict__ srt) {
  int i = blockIdx.x * blockDim.x + threadIdx.x;
  if (i < NT) {
    int s, d;
    if (i < NE) { s = src[i]; d = dst[i]; }
    else        { s = d = i - NE; }
    int pos = offs[d] + atomicAdd(&cur[d], 1);
    srt[pos] = s;
  }
}

// ==================== dual GEMM (R2 structure + pk_fma + b128 reads) ====================
// C1 = A@W1^T + b1, C2 = A@W2^T + b2.  A:[M,K] W:[FO,K] row-major.
// 256 threads. CT col-threads (4 cols each of both mats), 256/CT row-threads (8 rows each).
// CT=16: 128x64 tile.  CT=8: 256x32 tile (skinny FO).  K-tile = 16, 2 barriers/tile.

template <int CT>
__global__ __launch_bounds__(256)
void k_gemm_dual(const float* __restrict__ A, int M, int K, int FO,
                 const float* __restrict__ W1, const float* __restrict__ bias1,
                 const float* __restrict__ W2, const float* __restrict__ bias2,
                 float* __restrict__ C1, float* __restrict__ C2) {
  constexpr int BN = CT * 4;            // cols per tile
  constexpr int BR = (256 / CT) * 8;    // rows per tile
  constexpr int AF4 = BR / 64;          // A float4 per thread (2 or 4)
  __shared__ float As[16][BR + 4];
  __shared__ float Bs[2][16][BN + 4];

  int tid = threadIdx.x;
  int tx = tid % CT, ty = tid / CT;
  int mb = blockIdx.x * BR, nb = blockIdx.y * BN;
  int nkt = (K + 15) >> 4;
  bool kvec = ((K & 3) == 0);

  float4 sa[AF4], sb1, sb2;

  auto ldrow = [&](const float* P, int row, int lim, int k0, int kq) -> float4 {
    float4 v = make_float4(0.f, 0.f, 0.f, 0.f);
    if (row < lim) {
      if (kvec && k0 + kq + 3 < K) {
        v = *(const float4*)&P[(size_t)row * K + k0 + kq];
      } else {
        float t[4];
#pragma unroll
        for (int i = 0; i < 4; ++i)
          t[i] = (k0 + kq + i < K) ? P[(size_t)row * K + k0 + kq + i] : 0.f;
        v = make_float4(t[0], t[1], t[2], t[3]);
      }
    }
    return v;
  };

  auto loadg = [&](int kt) {
    int k0 = kt * 16;
#pragma unroll
    for (int q = 0; q < AF4; ++q) {
      int f4 = q * 256 + tid;
      sa[q] = ldrow(A, mb + (f4 >> 2), M, k0, (f4 & 3) * 4);
    }
    if constexpr (CT == 16) {
      int row = tid >> 2, kq = (tid & 3) * 4;
      sb1 = ldrow(W1, nb + row, FO, k0, kq);
      sb2 = ldrow(W2, nb + row, FO, k0, kq);
    } else {
      const float* W = (tid < 128) ? W1 : W2;
      int t = tid & 127;
      sb1 = ldrow(W, nb + (t >> 2), FO, k0, (t & 3) * 4);
    }
  };

  auto stlds = [&]() {
#pragma unroll
    for (int q = 0; q < AF4; ++q) {
      int f4 = q * 256 + tid;
      int row = f4 >> 2, kq = (f4 & 3) * 4;
      As[kq + 0][row] = sa[q].x; As[kq + 1][row] = sa[q].y;
      As[kq + 2][row] = sa[q].z; As[kq + 3][row] = sa[q].w;
    }
    if constexpr (CT == 16) {
      int row = tid >> 2, kq = (tid & 3) * 4;
      Bs[0][kq + 0][row] = sb1.x; Bs[0][kq + 1][row] = sb1.y;
      Bs[0][kq + 2][row] = sb1.z; Bs[0][kq + 3][row] = sb1.w;
      Bs[1][kq + 0][row] = sb2.x; Bs[1][kq + 1][row] = sb2.y;
      Bs[1][kq + 2][row] = sb2.z; Bs[1][kq + 3][row] = sb2.w;
    } else {
      int mat = (tid < 128) ? 0 : 1;
      int t = tid & 127;
      int row = t >> 2, kq = (t & 3) * 4;
      Bs[mat][kq + 0][row] = sb1.x; Bs[mat][kq + 1][row] = sb1.y;
      Bs[mat][kq + 2][row] = sb1.z; Bs[mat][kq + 3][row] = sb1.w;
    }
  };

  float2 c1[8][2], c2[8][2];
#pragma unroll
  for (int r = 0; r < 8; ++r)
#pragma unroll
    for (int j = 0; j < 2; ++j) {
      c1[r][j] = make_float2(0.f, 0.f);
      c2[r][j] = make_float2(0.f, 0.f);
    }

  loadg(0);
  stlds();
  __syncthreads();

  for (int t = 0;;) {
#pragma unroll
    for (int k = 0; k < 16; ++k) {
      float4 av0 = *(const float4*)&As[k][ty * 8 + 0];
      float4 av1 = *(const float4*)&As[k][ty * 8 + 4];
      float4 bv1 = *(const float4*)&Bs[0][k][tx * 4];
      float4 bv2 = *(const float4*)&Bs[1][k][tx * 4];
      float2 f1a = make_float2(bv1.x, bv1.y), f1b = make_float2(bv1.z, bv1.w);
      float2 f2a = make_float2(bv2.x, bv2.y), f2b = make_float2(bv2.z, bv2.w);
      float2 a01 = make_float2(av0.x, av0.y), a23 = make_float2(av0.z, av0.w);
      float2 a45 = make_float2(av1.x, av1.y), a67 = make_float2(av1.z, av1.w);
#define PKROW(rp, a)                                                       \
      pk_l(c1[2 * rp + 0][0], a, f1a); pk_l(c1[2 * rp + 0][1], a, f1b);    \
      pk_h(c1[2 * rp + 1][0], a, f1a); pk_h(c1[2 * rp + 1][1], a, f1b);    \
      pk_l(c2[2 * rp + 0][0], a, f2a); pk_l(c2[2 * rp + 0][1], a, f2b);    \
      pk_h(c2[2 * rp + 1][0], a, f2a); pk_h(c2[2 * rp + 1][1], a, f2b);
      PKROW(0, a01) PKROW(1, a23) PKROW(2, a45) PKROW(3, a67)
#undef PKROW
    }
    if (++t == nkt) break;
    loadg(t);
    __syncthreads();   // all waves done reading previous tile
    stlds();
    __syncthreads();   // tile ready
  }

  int col = nb + tx * 4;
  if (col < FO) {   // FO multiple of 4 in all layers
    float4 bb1 = *(const float4*)&bias1[col];
    float4 bb2 = *(const float4*)&bias2[col];
#pragma unroll
    for (int r = 0; r < 8; ++r) {
      int m = mb + ty * 8 + r;
      if (m >= M) continue;
      float4 o1 = make_float4(c1[r][0].x + bb1.x, c1[r][0].y + bb1.y,
                              c1[r][1].x + bb1.z, c1[r][1].y + bb1.w);
      float4 o2 = make_float4(c2[r][0].x + bb2.x, c2[r][0].y + bb2.y,
                              c2[r][1].x + bb2.z, c2[r][1].y + bb2.w);
      *(float4*)&C1[(size_t)m * FO + col] = o1;
      *(float4*)&C2[(size_t)m * FO + col] = o2;
    }
  }
}

// ==================== GAT edge phase, H=3 C=64: one node per 64-thread block ====================

#define LDX(s, X0, X1, X2) { int off_ = (s) * 192 + lane; \
  X0 = xl[off_]; X1 = xl[off_ + 64]; X2 = xl[off_ + 128]; }

__global__ __launch_bounds__(64)
void k_gat3(const float* __restrict__ xl, const float* __restrict__ xr,
            const float* __restrict__ att, const float* __restrict__ bias,
            const int* __restrict__ offs, const int* __restrict__ srt,
            float* __restrict__ out, int relu) {
  const float L2E = 1.4426950408889634f;
  int lane = threadIdx.x;
  int n = blockIdx.x;
  float xr0 = xr[n * 192 + lane], xr1 = xr[n * 192 + 64 + lane], xr2 = xr[n * 192 + 128 + lane];
  float at0 = att[lane] * L2E, at1 = att[64 + lane] * L2E, at2 = att[128 + lane] * L2E;
  float m0 = -1e30f, m1 = -1e30f, m2 = -1e30f;
  float d0 = 0.f, d1 = 0.f, d2 = 0.f;
  float a0 = 0.f, a1 = 0.f, a2 = 0.f;
  int e0 = offs[n], e1 = offs[n + 1];

  bool vA1 = (e0 + 1 < e1);
  int sA0 = srt[e0];
  int sA1 = vA1 ? srt[e0 + 1] : sA0;
  float XA0, XA1, XA2, XB0, XB1, XB2;
  LDX(sA0, XA0, XA1, XA2);
  LDX(sA1, XB0, XB1, XB2);

  for (int j = e0; j < e1; j += 2) {
    bool hn = (j + 2) < e1;
    bool vC1 = false;
    float YA0 = 0.f, YA1 = 0.f, YA2 = 0.f, YB0 = 0.f, YB1 = 0.f, YB2 = 0.f;
    if (hn) {
      int sC0 = srt[j + 2];
      vC1 = (j + 3 < e1);
      int sC1 = vC1 ? srt[j + 3] : sC0;
      LDX(sC0, YA0, YA1, YA2);
      LDX(sC1, YB0, YB1, YB2);
    }
    float r0 = lrelu(XA0 + xr0) * at0;
    float r1 = lrelu(XA1 + xr1) * at1;
    float r2 = lrelu(XA2 + xr2) * at2;
    float r3 = lrelu(XB0 + xr0) * at0;
    float r4 = lrelu(XB1 + xr1) * at1;
    float r5 = lrelu(XB2 + xr2) * at2;
    r0 = wave_sum(r0); r1 = wave_sum(r1); r2 = wave_sum(r2);
    r3 = wave_sum(r3); r4 = wave_sum(r4); r5 = wave_sum(r5);

    float eb0 = vA1 ? r3 : -1e30f;
    float eb1 = vA1 ? r4 : -1e30f;
    float eb2 = vA1 ? r5 : -1e30f;
    float pm0 = fmaxf(r0, eb0), pm1 = fmaxf(r1, eb1), pm2 = fmaxf(r2, eb2);
    float g = fmaxf(fmaxf(pm0 - m0, pm1 - m1), pm2 - m2);
    if (g > 11.0f) {   // rare rescale (defer-max); log2 domain
      float nm0 = fmaxf(m0, pm0), nm1 = fmaxf(m1, pm1), nm2 = fmaxf(m2, pm2);
      float s0 = exp2_fast(m0 - nm0), s1 = exp2_fast(m1 - nm1), s2 = exp2_fast(m2 - nm2);
      d0 *= s0; a0 *= s0; m0 = nm0;
      d1 *= s1; a1 *= s1; m1 = nm1;
      d2 *= s2; a2 *= s2; m2 = nm2;
    }
    float p00 = exp2_fast(r0 - m0), p10 = exp2_fast(eb0 - m0);
    float p01 = exp2_fast(r1 - m1), p11 = exp2_fast(eb1 - m1);
    float p02 = exp2_fast(r2 - m2), p12 = exp2_fast(eb2 - m2);
    d0 += p00 + p10;
    d1 += p01 + p11;
    d2 += p02 + p12;
    a0 = fmaf(p00, XA0, fmaf(p10, XB0, a0));
    a1 = fmaf(p01, XA1, fmaf(p11, XB1, a1));
    a2 = fmaf(p02, XA2, fmaf(p12, XB2, a2));
    if (hn) {
      XA0 = YA0; XA1 = YA1; XA2 = YA2;
      XB0 = YB0; XB1 = YB1; XB2 = YB2;
      vA1 = vC1;
    }
  }
  float v0 = a0 / d0 + bias[lane];
  float v1 = a1 / d1 + bias[64 + lane];
  float v2 = a2 / d2 + bias[128 + lane];
  if (relu) { v0 = fmaxf(v0, 0.f); v1 = fmaxf(v1, 0.f); v2 = fmaxf(v2, 0.f); }
  out[n * 192 + lane] = v0;
  out[n * 192 + 64 + lane] = v1;
  out[n * 192 + 128 + lane] = v2;
}

// ==================== GAT layer 3 (H=1, C=20) fused with global_add_pool ====================

__global__ __launch_bounds__(64)
void k_gat1(const float* __restrict__ xl, const float* __restrict__ xr,
            const float* __restrict__ att, const float* __restrict__ bias,
            const int* __restrict__ offs, const int* __restrict__ srt,
            const int* __restrict__ batch, float* __restrict__ gout) {
  const float L2E = 1.4426950408889634f;
  int lane = threadIdx.x;
  int n = blockIdx.x;
  int ll = (lane < 20) ? lane : 0;
  float xrv = xr[n * 20 + ll];
  float ats = (lane < 20) ? att[lane] * L2E : 0.f;
  float m = -1e30f, d = 0.f, acc = 0.f;
  int e0 = offs[n], e1 = offs[n + 1];

  bool vA1 = (e0 + 1 < e1);
  int sA0 = srt[e0];
  int sA1 = vA1 ? srt[e0 + 1] : sA0;
  float XA = xl[sA0 * 20 + ll];
  float XB = xl[sA1 * 20 + ll];

  for (int j = e0; j < e1; j += 2) {
    bool hn = (j + 2) < e1;
    bool vC1 = false;
    float YA = 0.f, YB = 0.f;
    if (hn) {
      int sC0 = srt[j + 2];
      vC1 = (j + 3 < e1);
      int sC1 = vC1 ? srt[j + 3] : sC0;
      YA = xl[sC0 * 20 + ll];
      YB = xl[sC1 * 20 + ll];
    }
    float r0 = lrelu(XA + xrv) * ats;
    float r1 = lrelu(XB + xrv) * ats;
    r0 = wave_sum(r0);
    r1 = wave_sum(r1);
    float eb = vA1 ? r1 : -1e30f;
    float pm = fmaxf(r0, eb);
    if (pm - m > 11.0f) {
      float nm = fmaxf(m, pm);
      float s = exp2_fast(m - nm);
      d *= s; acc *= s; m = nm;
    }
    float p0 = exp2_fast(r0 - m), p1 = exp2_fast(eb - m);
    d += p0 + p1;
    acc = fmaf(p0, XA, fmaf(p1, XB, acc));
    if (hn) { XA = YA; XB = YB; vA1 = vC1; }
  }
  if (lane < 20) {
    float v = acc / d + bias[lane];
    atomicAdd(&gout[batch[n] * 20 + lane], v);
  }
}

// ==================== launch ====================

extern "C" void kernel_launch(void* const* d_in, const int* in_sizes, int n_in,
                              void* d_out, int out_size, void* d_ws, size_t ws_size,
                              hipStream_t stream) {
  const float* x = (const float*)d_in[0];
  const int* src = (const int*)d_in[1];
  const int* dst = src + NE;
  const int* batch = (const int*)d_in[2];
  const float *Wl[4], *bl[4], *Wr[4], *br[4], *att[4], *bb[4];
  for (int li = 0; li < 4; ++li) {
    Wl[li]  = (const float*)d_in[3 + li * 6 + 0];
    bl[li]  = (const float*)d_in[3 + li * 6 + 1];
    Wr[li]  = (const float*)d_in[3 + li * 6 + 2];
    br[li]  = (const float*)d_in[3 + li * 6 + 3];
    att[li] = (const float*)d_in[3 + li * 6 + 4];
    bb[li]  = (const float*)d_in[3 + li * 6 + 5];
  }

  char* p = (char*)d_ws;
  auto alloc = [&](size_t bytes) {
    char* r = p;
    p += (bytes + 255) & ~(size_t)255;
    return r;
  };
  float* xl  = (float*)alloc((size_t)NN * 192 * 4);
  float* xr  = (float*)alloc((size_t)NN * 192 * 4);
  float* hb  = (float*)alloc((size_t)NN * 192 * 4);
  int* srt   = (int*)alloc((size_t)NT * 4);
  int* offs  = (int*)alloc((size_t)(NN + 1) * 4);
  int* cnt   = (int*)alloc((size_t)NN * 4);
  int* cur   = (int*)alloc((size_t)NN * 4);

  hipMemsetAsync(cnt, 0, (size_t)NN * 4, stream);
  hipMemsetAsync(cur, 0, (size_t)NN * 4, stream);
  hipMemsetAsync(d_out, 0, (size_t)NG * 20 * 4, stream);

  k_hist<<<(NT + 255) / 256, 256, 0, stream>>>(dst, cnt);
  k_scan<<<1, 1024, 0, stream>>>(cnt, offs);
  k_scatter<<<(NT + 255) / 256, 256, 0, stream>>>(src, dst, offs, cur, srt);

  // layer 0: FI=11, FO=192
  {
    dim3 g((NN + 127) / 128, 3);
    k_gemm_dual<16><<<g, 256, 0, stream>>>(x, NN, 11, 192, Wl[0], bl[0], Wr[0], br[0], xl, xr);
    k_gat3<<<NN, 64, 0, stream>>>(xl, xr, att[0], bb[0], offs, srt, hb, 1);
  }
  // layers 1,2: FI=192, FO=192
  for (int li = 1; li <= 2; ++li) {
    dim3 g((NN + 127) / 128, 3);
    k_gemm_dual<16><<<g, 256, 0, stream>>>(hb, NN, 192, 192, Wl[li], bl[li], Wr[li], br[li], xl, xr);
    k_gat3<<<NN, 64, 0, stream>>>(xl, xr, att[li], bb[li], offs, srt, hb, 1);
  }
  // layer 3: FI=192, FO=20, skinny tile (256x32), fused pool
  {
    dim3 g((NN + 255) / 256, 1);
    k_gemm_dual<8><<<g, 256, 0, stream>>>(hb, NN, 192, 20, Wl[3], bl[3], Wr[3], br[3], xl, xr);
    k_gat1<<<NN, 64, 0, stream>>>(xl, xr, att[3], bb[3], offs, srt, batch, (float*)d_out);
  }
}

// Round 6
// 663.262 us; speedup vs baseline: 1.7818x; 1.2468x over previous
//
#include <hip/hip_runtime.h>

#define NN 50000
#define NE 800000
#define NT 850000   // NE + NN self loops
#define NG 512

typedef __attribute__((ext_vector_type(8))) short bf16x8;
typedef __attribute__((ext_vector_type(4))) float f32x4;

// ==================== reduction / math helpers ====================

template <int CTRL>
__device__ __forceinline__ float dpp_add(float x) {
  int y = __builtin_amdgcn_update_dpp(0, __float_as_int(x), CTRL, 0xF, 0xF, true);
  return x + __int_as_float(y);
}

// full 64-lane sum, broadcast to all lanes
__device__ __forceinline__ float wave_sum(float x) {
  x = dpp_add<0xB1>(x);    // quad_perm [1,0,3,2]  (xor1)
  x = dpp_add<0x4E>(x);    // quad_perm [2,3,0,1]  (xor2)
  x = dpp_add<0x124>(x);   // row_ror:4
  x = dpp_add<0x128>(x);   // row_ror:8
  x = x + __int_as_float(__builtin_amdgcn_ds_swizzle(__float_as_int(x), 0x401F)); // xor16
  auto p = __builtin_amdgcn_permlane32_swap(__float_as_uint(x), __float_as_uint(x), false, false);
  return __uint_as_float(p[0]) + __uint_as_float(p[1]);   // + xor32
}

__device__ __forceinline__ float exp2_fast(float x) {
#if __has_builtin(__builtin_amdgcn_exp2f)
  return __builtin_amdgcn_exp2f(x);
#else
  return exp2f(x);
#endif
}

__device__ __forceinline__ float lrelu(float t) { return fmaxf(t, 0.2f * t); }

// f32 -> bf16 (RNE)
__device__ __forceinline__ unsigned short f2bf(float f) {
  unsigned int u = __float_as_uint(f);
  u = (u + 0x7FFFu + ((u >> 16) & 1u)) >> 16;
  return (unsigned short)u;
}

// packed f32 FMA: d += a.{lo or hi broadcast} * b (per-component)
__device__ __forceinline__ void pk_l(float2& d, float2 a, float2 b) {
  asm("v_pk_fma_f32 %0, %1, %2, %0 op_sel_hi:[0,1,1]" : "+v"(d) : "v"(a), "v"(b));
}
__device__ __forceinline__ void pk_h(float2& d, float2 a, float2 b) {
  asm("v_pk_fma_f32 %0, %1, %2, %0 op_sel:[1,0,0]" : "+v"(d) : "v"(a), "v"(b));
}

// ==================== edge bucket sort (by dst) ====================

__global__ void k_hist(const int* __restrict__ dst, int* __restrict__ cnt) {
  int i = blockIdx.x * blockDim.x + threadIdx.x;
  if (i < NT) {
    int d = (i < NE) ? dst[i] : (i - NE);
    atomicAdd(&cnt[d], 1);
  }
}

__global__ __launch_bounds__(1024)
void k_scan(const int* __restrict__ cnt, int* __restrict__ offs) {
  __shared__ int sh[1024];
  int tid = threadIdx.x;
  const int CH = (NN + 1023) / 1024;
  int base = tid * CH;
  int s = 0;
  for (int i = 0; i < CH; ++i) {
    int idx = base + i;
    if (idx < NN) s += cnt[idx];
  }
  sh[tid] = s;
  __syncthreads();
  for (int off = 1; off < 1024; off <<= 1) {
    int t = (tid >= off) ? sh[tid - off] : 0;
    __syncthreads();
    sh[tid] += t;
    __syncthreads();
  }
  int prefix = (tid > 0) ? sh[tid - 1] : 0;
  for (int i = 0; i < CH; ++i) {
    int idx = base + i;
    if (idx < NN) {
      offs[idx] = prefix;
      prefix += cnt[idx];
    }
  }
  if (tid == 1023) offs[NN] = sh[1023];
}

__global__ void k_scatter(const int* __restrict__ src, const int* __restrict__ dst,
                          const int* __restrict__ offs, int* __restrict__ cur,
                          int* __restrict__ srt) {
  int i = blockIdx.x * blockDim.x + threadIdx.x;
  if (i < NT) {
    int s, d;
    if (i < NE) { s = src[i]; d = dst[i]; }
    else        { s = d = i - NE; }
    int pos = offs[d] + atomicAdd(&cur[d], 1);
    srt[pos] = s;
  }
}

// ==================== weight convert (f32 -> bf16), all layers 1..3 ====================
// wb layout (shorts): [Wl1 36864][Wr1 36864][Wl2 36864][Wr2 36864][Wl3 3840][Wr3 3840]

__global__ void k_cvtW(const float* __restrict__ a, const float* __restrict__ b,
                       const float* __restrict__ c, const float* __restrict__ d,
                       const float* __restrict__ e, const float* __restrict__ f,
                       unsigned short* __restrict__ out) {
  int i = blockIdx.x * 256 + threadIdx.x;
  if (i >= 155136) return;
  float v;
  if      (i < 36864)  v = a[i];
  else if (i < 73728)  v = b[i - 36864];
  else if (i < 110592) v = c[i - 73728];
  else if (i < 147456) v = d[i - 110592];
  else if (i < 151296) v = e[i - 147456];
  else                 v = f[i - 151296];
  out[i] = f2bf(v);
}

// ==================== MFMA GEMM: C = A_bf16 @ W_bf16^T + bias  (K=192) ====================
// A:[M,192] bf16; W:[FO,192] bf16; C:[M,FO] f32.  Tile 64 rows x 64 cols, 4 waves (2x2),
// whole K resident in LDS (no k-loop staging, one barrier).

#define LSTR 200  // LDS row stride in bf16 (192 + 8 pad -> balanced banks)

__global__ __launch_bounds__(256)
void k_gemm_mfma(const unsigned short* __restrict__ Abf,
                 const unsigned short* __restrict__ Wbf,
                 const float* __restrict__ bias,
                 float* __restrict__ C, int M, int FO) {
  __shared__ unsigned short Al[64 * LSTR];
  __shared__ unsigned short Bl[64 * LSTR];
  int tid = threadIdx.x;
  int mb = blockIdx.x * 64;
  int nb = blockIdx.y * 64;

  // stage: thread t handles row r = t>>2, quarter q = t&3 (48 bf16 = 6 x b128)
  {
    int r = tid >> 2, q = tid & 3;
    int ga = mb + r; if (ga >= M) ga = M - 1;
    int gb = nb + r; if (gb >= FO) gb = FO - 1;
    const unsigned short* pA = Abf + (size_t)ga * 192 + q * 48;
    const unsigned short* pB = Wbf + (size_t)gb * 192 + q * 48;
    unsigned short* lA = Al + r * LSTR + q * 48;
    unsigned short* lB = Bl + r * LSTR + q * 48;
#pragma unroll
    for (int i = 0; i < 6; ++i) {
      *(bf16x8*)(lA + i * 8) = *(const bf16x8*)(pA + i * 8);
      *(bf16x8*)(lB + i * 8) = *(const bf16x8*)(pB + i * 8);
    }
  }
  __syncthreads();

  int l = tid & 63, wid = tid >> 6;
  int wr = (wid >> 1) * 32, wc = (wid & 1) * 32;
  int lr = l & 15, lk = (l >> 4) * 8;

  f32x4 acc00 = {0.f, 0.f, 0.f, 0.f}, acc01 = acc00, acc10 = acc00, acc11 = acc00;
  const unsigned short* pa0 = Al + (wr + 0 + lr) * LSTR + lk;
  const unsigned short* pa1 = Al + (wr + 16 + lr) * LSTR + lk;
  const unsigned short* pb0 = Bl + (wc + 0 + lr) * LSTR + lk;
  const unsigned short* pb1 = Bl + (wc + 16 + lr) * LSTR + lk;
#pragma unroll
  for (int kt = 0; kt < 6; ++kt) {
    bf16x8 a0 = *(const bf16x8*)(pa0 + kt * 32);
    bf16x8 a1 = *(const bf16x8*)(pa1 + kt * 32);
    bf16x8 b0 = *(const bf16x8*)(pb0 + kt * 32);
    bf16x8 b1 = *(const bf16x8*)(pb1 + kt * 32);
    acc00 = __builtin_amdgcn_mfma_f32_16x16x32_bf16(a0, b0, acc00, 0, 0, 0);
    acc01 = __builtin_amdgcn_mfma_f32_16x16x32_bf16(a0, b1, acc01, 0, 0, 0);
    acc10 = __builtin_amdgcn_mfma_f32_16x16x32_bf16(a1, b0, acc10, 0, 0, 0);
    acc11 = __builtin_amdgcn_mfma_f32_16x16x32_bf16(a1, b1, acc11, 0, 0, 0);
  }

  // C/D layout: col = lane&15, row = (lane>>4)*4 + reg   [m89-verified]
  int rb = (l >> 4) * 4;
#pragma unroll
  for (int fm = 0; fm < 2; ++fm) {
#pragma unroll
    for (int fn = 0; fn < 2; ++fn) {
      const f32x4& av = fm == 0 ? (fn == 0 ? acc00 : acc01) : (fn == 0 ? acc10 : acc11);
      int col = nb + wc + fn * 16 + lr;
      if (col >= FO) continue;
      float bv = bias[col];
#pragma unroll
      for (int i = 0; i < 4; ++i) {
        int row = mb + wr + fm * 16 + rb + i;
        if (row < M) C[(size_t)row * FO + col] = av[i] + bv;
      }
    }
  }
}

// ==================== f32 dual GEMM (layer 0 only, K=11) ====================

template <int CT>
__global__ __launch_bounds__(256)
void k_gemm_dual(const float* __restrict__ A, int M, int K, int FO,
                 const float* __restrict__ W1, const float* __restrict__ bias1,
                 const float* __restrict__ W2, const float* __restrict__ bias2,
                 float* __restrict__ C1, float* __restrict__ C2) {
  constexpr int BN = CT * 4;
  constexpr int BR = (256 / CT) * 8;
  constexpr int AF4 = BR / 64;
  __shared__ float As[16][BR + 4];
  __shared__ float Bs[2][16][BN + 4];

  int tid = threadIdx.x;
  int tx = tid % CT, ty = tid / CT;
  int mb = blockIdx.x * BR, nb = blockIdx.y * BN;
  int nkt = (K + 15) >> 4;
  bool kvec = ((K & 3) == 0);

  float4 sa[AF4], sb1, sb2;

  auto ldrow = [&](const float* P, int row, int lim, int k0, int kq) -> float4 {
    float4 v = make_float4(0.f, 0.f, 0.f, 0.f);
    if (row < lim) {
      if (kvec && k0 + kq + 3 < K) {
        v = *(const float4*)&P[(size_t)row * K + k0 + kq];
      } else {
        float t[4];
#pragma unroll
        for (int i = 0; i < 4; ++i)
          t[i] = (k0 + kq + i < K) ? P[(size_t)row * K + k0 + kq + i] : 0.f;
        v = make_float4(t[0], t[1], t[2], t[3]);
      }
    }
    return v;
  };

  auto loadg = [&](int kt) {
    int k0 = kt * 16;
#pragma unroll
    for (int q = 0; q < AF4; ++q) {
      int f4 = q * 256 + tid;
      sa[q] = ldrow(A, mb + (f4 >> 2), M, k0, (f4 & 3) * 4);
    }
    int row = tid >> 2, kq = (tid & 3) * 4;
    sb1 = ldrow(W1, nb + row, FO, k0, kq);
    sb2 = ldrow(W2, nb + row, FO, k0, kq);
  };

  auto stlds = [&]() {
#pragma unroll
    for (int q = 0; q < AF4; ++q) {
      int f4 = q * 256 + tid;
      int row = f4 >> 2, kq = (f4 & 3) * 4;
      As[kq + 0][row] = sa[q].x; As[kq + 1][row] = sa[q].y;
      As[kq + 2][row] = sa[q].z; As[kq + 3][row] = sa[q].w;
    }
    int row = tid >> 2, kq = (tid & 3) * 4;
    Bs[0][kq + 0][row] = sb1.x; Bs[0][kq + 1][row] = sb1.y;
    Bs[0][kq + 2][row] = sb1.z; Bs[0][kq + 3][row] = sb1.w;
    Bs[1][kq + 0][row] = sb2.x; Bs[1][kq + 1][row] = sb2.y;
    Bs[1][kq + 2][row] = sb2.z; Bs[1][kq + 3][row] = sb2.w;
  };

  float2 c1[8][2], c2[8][2];
#pragma unroll
  for (int r = 0; r < 8; ++r)
#pragma unroll
    for (int j = 0; j < 2; ++j) {
      c1[r][j] = make_float2(0.f, 0.f);
      c2[r][j] = make_float2(0.f, 0.f);
    }

  loadg(0);
  stlds();
  __syncthreads();

  for (int t = 0;;) {
#pragma unroll
    for (int k = 0; k < 16; ++k) {
      float4 av0 = *(const float4*)&As[k][ty * 8 + 0];
      float4 av1 = *(const float4*)&As[k][ty * 8 + 4];
      float4 bv1 = *(const float4*)&Bs[0][k][tx * 4];
      float4 bv2 = *(const float4*)&Bs[1][k][tx * 4];
      float2 f1a = make_float2(bv1.x, bv1.y), f1b = make_float2(bv1.z, bv1.w);
      float2 f2a = make_float2(bv2.x, bv2.y), f2b = make_float2(bv2.z, bv2.w);
      float2 a01 = make_float2(av0.x, av0.y), a23 = make_float2(av0.z, av0.w);
      float2 a45 = make_float2(av1.x, av1.y), a67 = make_float2(av1.z, av1.w);
#define PKROW(rp, a)                                                       \
      pk_l(c1[2 * rp + 0][0], a, f1a); pk_l(c1[2 * rp + 0][1], a, f1b);    \
      pk_h(c1[2 * rp + 1][0], a, f1a); pk_h(c1[2 * rp + 1][1], a, f1b);    \
      pk_l(c2[2 * rp + 0][0], a, f2a); pk_l(c2[2 * rp + 0][1], a, f2b);    \
      pk_h(c2[2 * rp + 1][0], a, f2a); pk_h(c2[2 * rp + 1][1], a, f2b);
      PKROW(0, a01) PKROW(1, a23) PKROW(2, a45) PKROW(3, a67)
#undef PKROW
    }
    if (++t == nkt) break;
    loadg(t);
    __syncthreads();
    stlds();
    __syncthreads();
  }

  int col = nb + tx * 4;
  if (col < FO) {
    float4 bb1 = *(const float4*)&bias1[col];
    float4 bb2 = *(const float4*)&bias2[col];
#pragma unroll
    for (int r = 0; r < 8; ++r) {
      int m = mb + ty * 8 + r;
      if (m >= M) continue;
      float4 o1 = make_float4(c1[r][0].x + bb1.x, c1[r][0].y + bb1.y,
                              c1[r][1].x + bb1.z, c1[r][1].y + bb1.w);
      float4 o2 = make_float4(c2[r][0].x + bb2.x, c2[r][0].y + bb2.y,
                              c2[r][1].x + bb2.z, c2[r][1].y + bb2.w);
      *(float4*)&C1[(size_t)m * FO + col] = o1;
      *(float4*)&C2[(size_t)m * FO + col] = o2;
    }
  }
}

// ==================== GAT edge phase, H=3 C=64: one node per 64-thread block ====================
// output written as bf16 (input to next layer's MFMA GEMM)

#define LDX(s, X0, X1, X2) { int off_ = (s) * 192 + lane; \
  X0 = xl[off_]; X1 = xl[off_ + 64]; X2 = xl[off_ + 128]; }

__global__ __launch_bounds__(64)
void k_gat3(const float* __restrict__ xl, const float* __restrict__ xr,
            const float* __restrict__ att, const float* __restrict__ bias,
            const int* __restrict__ offs, const int* __restrict__ srt,
            unsigned short* __restrict__ obf, int relu) {
  const float L2E = 1.4426950408889634f;
  int lane = threadIdx.x;
  int n = blockIdx.x;
  float xr0 = xr[n * 192 + lane], xr1 = xr[n * 192 + 64 + lane], xr2 = xr[n * 192 + 128 + lane];
  float at0 = att[lane] * L2E, at1 = att[64 + lane] * L2E, at2 = att[128 + lane] * L2E;
  float m0 = -1e30f, m1 = -1e30f, m2 = -1e30f;
  float d0 = 0.f, d1 = 0.f, d2 = 0.f;
  float a0 = 0.f, a1 = 0.f, a2 = 0.f;
  int e0 = offs[n], e1 = offs[n + 1];

  bool vA1 = (e0 + 1 < e1);
  int sA0 = srt[e0];
  int sA1 = vA1 ? srt[e0 + 1] : sA0;
  float XA0, XA1, XA2, XB0, XB1, XB2;
  LDX(sA0, XA0, XA1, XA2);
  LDX(sA1, XB0, XB1, XB2);

  for (int j = e0; j < e1; j += 2) {
    bool hn = (j + 2) < e1;
    bool vC1 = false;
    float YA0 = 0.f, YA1 = 0.f, YA2 = 0.f, YB0 = 0.f, YB1 = 0.f, YB2 = 0.f;
    if (hn) {
      int sC0 = srt[j + 2];
      vC1 = (j + 3 < e1);
      int sC1 = vC1 ? srt[j + 3] : sC0;
      LDX(sC0, YA0, YA1, YA2);
      LDX(sC1, YB0, YB1, YB2);
    }
    float r0 = lrelu(XA0 + xr0) * at0;
    float r1 = lrelu(XA1 + xr1) * at1;
    float r2 = lrelu(XA2 + xr2) * at2;
    float r3 = lrelu(XB0 + xr0) * at0;
    float r4 = lrelu(XB1 + xr1) * at1;
    float r5 = lrelu(XB2 + xr2) * at2;
    r0 = wave_sum(r0); r1 = wave_sum(r1); r2 = wave_sum(r2);
    r3 = wave_sum(r3); r4 = wave_sum(r4); r5 = wave_sum(r5);

    float eb0 = vA1 ? r3 : -1e30f;
    float eb1 = vA1 ? r4 : -1e30f;
    float eb2 = vA1 ? r5 : -1e30f;
    float pm0 = fmaxf(r0, eb0), pm1 = fmaxf(r1, eb1), pm2 = fmaxf(r2, eb2);
    float g = fmaxf(fmaxf(pm0 - m0, pm1 - m1), pm2 - m2);
    if (g > 11.0f) {   // rare rescale (defer-max); log2 domain
      float nm0 = fmaxf(m0, pm0), nm1 = fmaxf(m1, pm1), nm2 = fmaxf(m2, pm2);
      float s0 = exp2_fast(m0 - nm0), s1 = exp2_fast(m1 - nm1), s2 = exp2_fast(m2 - nm2);
      d0 *= s0; a0 *= s0; m0 = nm0;
      d1 *= s1; a1 *= s1; m1 = nm1;
      d2 *= s2; a2 *= s2; m2 = nm2;
    }
    float p00 = exp2_fast(r0 - m0), p10 = exp2_fast(eb0 - m0);
    float p01 = exp2_fast(r1 - m1), p11 = exp2_fast(eb1 - m1);
    float p02 = exp2_fast(r2 - m2), p12 = exp2_fast(eb2 - m2);
    d0 += p00 + p10;
    d1 += p01 + p11;
    d2 += p02 + p12;
    a0 = fmaf(p00, XA0, fmaf(p10, XB0, a0));
    a1 = fmaf(p01, XA1, fmaf(p11, XB1, a1));
    a2 = fmaf(p02, XA2, fmaf(p12, XB2, a2));
    if (hn) {
      XA0 = YA0; XA1 = YA1; XA2 = YA2;
      XB0 = YB0; XB1 = YB1; XB2 = YB2;
      vA1 = vC1;
    }
  }
  float v0 = a0 / d0 + bias[lane];
  float v1 = a1 / d1 + bias[64 + lane];
  float v2 = a2 / d2 + bias[128 + lane];
  if (relu) { v0 = fmaxf(v0, 0.f); v1 = fmaxf(v1, 0.f); v2 = fmaxf(v2, 0.f); }
  obf[n * 192 + lane] = f2bf(v0);
  obf[n * 192 + 64 + lane] = f2bf(v1);
  obf[n * 192 + 128 + lane] = f2bf(v2);
}

// ==================== GAT layer 3 (H=1, C=20) fused with global_add_pool ====================

__global__ __launch_bounds__(64)
void k_gat1(const float* __restrict__ xl, const float* __restrict__ xr,
            const float* __restrict__ att, const float* __restrict__ bias,
            const int* __restrict__ offs, const int* __restrict__ srt,
            const int* __restrict__ batch, float* __restrict__ gout) {
  const float L2E = 1.4426950408889634f;
  int lane = threadIdx.x;
  int n = blockIdx.x;
  int ll = (lane < 20) ? lane : 0;
  float xrv = xr[n * 20 + ll];
  float ats = (lane < 20) ? att[lane] * L2E : 0.f;
  float m = -1e30f, d = 0.f, acc = 0.f;
  int e0 = offs[n], e1 = offs[n + 1];

  bool vA1 = (e0 + 1 < e1);
  int sA0 = srt[e0];
  int sA1 = vA1 ? srt[e0 + 1] : sA0;
  float XA = xl[sA0 * 20 + ll];
  float XB = xl[sA1 * 20 + ll];

  for (int j = e0; j < e1; j += 2) {
    bool hn = (j + 2) < e1;
    bool vC1 = false;
    float YA = 0.f, YB = 0.f;
    if (hn) {
      int sC0 = srt[j + 2];
      vC1 = (j + 3 < e1);
      int sC1 = vC1 ? srt[j + 3] : sC0;
      YA = xl[sC0 * 20 + ll];
      YB = xl[sC1 * 20 + ll];
    }
    float r0 = lrelu(XA + xrv) * ats;
    float r1 = lrelu(XB + xrv) * ats;
    r0 = wave_sum(r0);
    r1 = wave_sum(r1);
    float eb = vA1 ? r1 : -1e30f;
    float pm = fmaxf(r0, eb);
    if (pm - m > 11.0f) {
      float nm = fmaxf(m, pm);
      float s = exp2_fast(m - nm);
      d *= s; acc *= s; m = nm;
    }
    float p0 = exp2_fast(r0 - m), p1 = exp2_fast(eb - m);
    d += p0 + p1;
    acc = fmaf(p0, XA, fmaf(p1, XB, acc));
    if (hn) { XA = YA; XB = YB; vA1 = vC1; }
  }
  if (lane < 20) {
    float v = acc / d + bias[lane];
    atomicAdd(&gout[batch[n] * 20 + lane], v);
  }
}

// ==================== launch ====================

extern "C" void kernel_launch(void* const* d_in, const int* in_sizes, int n_in,
                              void* d_out, int out_size, void* d_ws, size_t ws_size,
                              hipStream_t stream) {
  const float* x = (const float*)d_in[0];
  const int* src = (const int*)d_in[1];
  const int* dst = src + NE;
  const int* batch = (const int*)d_in[2];
  const float *Wl[4], *bl[4], *Wr[4], *br[4], *att[4], *bb[4];
  for (int li = 0; li < 4; ++li) {
    Wl[li]  = (const float*)d_in[3 + li * 6 + 0];
    bl[li]  = (const float*)d_in[3 + li * 6 + 1];
    Wr[li]  = (const float*)d_in[3 + li * 6 + 2];
    br[li]  = (const float*)d_in[3 + li * 6 + 3];
    att[li] = (const float*)d_in[3 + li * 6 + 4];
    bb[li]  = (const float*)d_in[3 + li * 6 + 5];
  }

  char* p = (char*)d_ws;
  auto alloc = [&](size_t bytes) {
    char* r = p;
    p += (bytes + 255) & ~(size_t)255;
    return r;
  };
  float* xl  = (float*)alloc((size_t)NN * 192 * 4);
  float* xr  = (float*)alloc((size_t)NN * 192 * 4);
  unsigned short* hbf = (unsigned short*)alloc((size_t)NN * 192 * 2);
  unsigned short* wb  = (unsigned short*)alloc((size_t)155136 * 2);
  int* srt   = (int*)alloc((size_t)NT * 4);
  int* offs  = (int*)alloc((size_t)(NN + 1) * 4);
  int* cnt   = (int*)alloc((size_t)NN * 4);
  int* cur   = (int*)alloc((size_t)NN * 4);

  hipMemsetAsync(cnt, 0, (size_t)NN * 4, stream);
  hipMemsetAsync(cur, 0, (size_t)NN * 4, stream);
  hipMemsetAsync(d_out, 0, (size_t)NG * 20 * 4, stream);

  k_hist<<<(NT + 255) / 256, 256, 0, stream>>>(dst, cnt);
  k_scan<<<1, 1024, 0, stream>>>(cnt, offs);
  k_scatter<<<(NT + 255) / 256, 256, 0, stream>>>(src, dst, offs, cur, srt);
  k_cvtW<<<(155136 + 255) / 256, 256, 0, stream>>>(Wl[1], Wr[1], Wl[2], Wr[2], Wl[3], Wr[3], wb);

  // layer 0: FI=11, FO=192 (f32 GEMM, K=11)
  {
    dim3 g((NN + 127) / 128, 3);
    k_gemm_dual<16><<<g, 256, 0, stream>>>(x, NN, 11, 192, Wl[0], bl[0], Wr[0], br[0], xl, xr);
    k_gat3<<<NN, 64, 0, stream>>>(xl, xr, att[0], bb[0], offs, srt, hbf, 1);
  }
  // layers 1,2: FI=192, FO=192 (bf16 MFMA GEMM)
  {
    dim3 gm((NN + 63) / 64, 3);
    k_gemm_mfma<<<gm, 256, 0, stream>>>(hbf, wb + 0,     bl[1], xl, NN, 192);
    k_gemm_mfma<<<gm, 256, 0, stream>>>(hbf, wb + 36864, br[1], xr, NN, 192);
    k_gat3<<<NN, 64, 0, stream>>>(xl, xr, att[1], bb[1], offs, srt, hbf, 1);
    k_gemm_mfma<<<gm, 256, 0, stream>>>(hbf, wb + 73728,  bl[2], xl, NN, 192);
    k_gemm_mfma<<<gm, 256, 0, stream>>>(hbf, wb + 110592, br[2], xr, NN, 192);
    k_gat3<<<NN, 64, 0, stream>>>(xl, xr, att[2], bb[2], offs, srt, hbf, 1);
  }
  // layer 3: FI=192, FO=20 (bf16 MFMA GEMM), fused pool
  {
    dim3 gm((NN + 63) / 64, 1);
    k_gemm_mfma<<<gm, 256, 0, stream>>>(hbf, wb + 147456, bl[3], xl, NN, 20);
    k_gemm_mfma<<<gm, 256, 0, stream>>>(hbf, wb + 151296, br[3], xr, NN, 20);
    k_gat1<<<NN, 64, 0, stream>>>(xl, xr, att[3], bb[3], offs, srt, batch, (float*)d_out);
  }
}